// Round 1
// baseline (649.198 us; speedup 1.0000x reference)
//
#include <hip/hip_runtime.h>
#include <hip/hip_bf16.h>
#include <math.h>

#define NH 12
#define SEQ 1024
#define HD 64
#define HDIM 768
#define BSZ 4
#define RK 129
#define FMIN -3.4028234663852886e38f

__device__ inline float dot4(float4 a, float4 b) {
    return fmaf(a.x, b.x, fmaf(a.y, b.y, fmaf(a.z, b.z, a.w * b.w)));
}

// ---------------- Kernel 1: fused QKV projection (fp32 tiled GEMM) ----------
// Y = X @ W + b, X:[4096,768], W:[768,768]. Output written as [B][nh][S][hd].
#define BM 128
#define BN 128
#define BK 16

__global__ __launch_bounds__(256) void qkv_gemm_kernel(
    const float* __restrict__ X,
    const float* __restrict__ Wq, const float* __restrict__ bq,
    const float* __restrict__ Wk, const float* __restrict__ bk,
    const float* __restrict__ Wv, const float* __restrict__ bv,
    float* __restrict__ Qo, float* __restrict__ Ko, float* __restrict__ Vo)
{
    const int which = blockIdx.z;
    const float* __restrict__ W    = (which == 0) ? Wq : (which == 1) ? Wk : Wv;
    const float* __restrict__ bias = (which == 0) ? bq : (which == 1) ? bk : bv;
    float* __restrict__ Y          = (which == 0) ? Qo : (which == 1) ? Ko : Vo;

    __shared__ float sA[BK][BM + 4];
    __shared__ float sB[BK][BN + 4];

    const int t  = threadIdx.x;
    const int m0 = blockIdx.x * BM;
    const int n0 = blockIdx.y * BN;
    const int tx = t & 15;
    const int ty = t >> 4;

    float c[8][8];
#pragma unroll
    for (int i = 0; i < 8; ++i)
#pragma unroll
        for (int j = 0; j < 8; ++j) c[i][j] = 0.0f;

    const int arow = t >> 2;         // 0..63
    const int acol = (t & 3) * 4;    // 0,4,8,12
    const int brow = t >> 5;         // 0..7
    const int bcol = (t & 31) * 4;   // 0..124

    for (int k0 = 0; k0 < HDIM; k0 += BK) {
        __syncthreads();
#pragma unroll
        for (int rr = 0; rr < 2; ++rr) {
            float4 a = *(const float4*)&X[(size_t)(m0 + rr * 64 + arow) * HDIM + k0 + acol];
            sA[acol + 0][rr * 64 + arow] = a.x;
            sA[acol + 1][rr * 64 + arow] = a.y;
            sA[acol + 2][rr * 64 + arow] = a.z;
            sA[acol + 3][rr * 64 + arow] = a.w;
        }
#pragma unroll
        for (int rr = 0; rr < 2; ++rr) {
            *(float4*)&sB[rr * 8 + brow][bcol] =
                *(const float4*)&W[(size_t)(k0 + rr * 8 + brow) * HDIM + n0 + bcol];
        }
        __syncthreads();
#pragma unroll
        for (int kk = 0; kk < BK; ++kk) {
            float a[8], b[8];
            *(float4*)&a[0] = *(float4*)&sA[kk][ty * 8];
            *(float4*)&a[4] = *(float4*)&sA[kk][ty * 8 + 4];
            *(float4*)&b[0] = *(float4*)&sB[kk][tx * 4];
            *(float4*)&b[4] = *(float4*)&sB[kk][64 + tx * 4];
#pragma unroll
            for (int i = 0; i < 8; ++i)
#pragma unroll
                for (int j = 0; j < 8; ++j)
                    c[i][j] = fmaf(a[i], b[j], c[i][j]);
        }
    }

    // epilogue: bias + scatter to [B][nh][S][hd]
#pragma unroll
    for (int i = 0; i < 8; ++i) {
        int m  = m0 + ty * 8 + i;
        int bb = m >> 10;
        int ss = m & 1023;
#pragma unroll
        for (int jg = 0; jg < 2; ++jg) {
            int n  = n0 + jg * 64 + tx * 4;
            int hh = n >> 6;
            int dd = n & 63;
            float4 bv4 = *(const float4*)&bias[n];
            float4 o;
            o.x = c[i][jg * 4 + 0] + bv4.x;
            o.y = c[i][jg * 4 + 1] + bv4.y;
            o.z = c[i][jg * 4 + 2] + bv4.z;
            o.w = c[i][jg * 4 + 3] + bv4.w;
            size_t off = ((size_t)(bb * NH + hh) * SEQ + ss) * HD + dd;
            *(float4*)&Y[off] = o;
        }
    }
}

// ---------------- Kernel 2: flash-style attention with relative positions --
// Block = 256 threads = 64 query rows x 4 lanes (16-dim slice each).
// K/V tiles of 64 keys staged in LDS. Online softmax per row. Band terms
// (|j-i|<=64) add q.E_key[rel] to the score and p*E_val[rel] to the context.
__global__ __launch_bounds__(256) void attn_kernel(
    const float* __restrict__ Q, const float* __restrict__ K,
    const float* __restrict__ V, const float* __restrict__ mask,
    const float* __restrict__ Ek, const float* __restrict__ Ev,
    float* __restrict__ out)
{
    const int b  = blockIdx.z;
    const int h  = blockIdx.y;
    const int i0 = blockIdx.x * 64;
    const int t  = threadIdx.x;
    const int r  = t >> 2;      // row within block: 0..63
    const int sl = t & 3;       // 16-dim slice: 0..3
    const int i  = i0 + r;      // global query row
    const int bh = b * NH + h;

    __shared__ float sK[64][68];
    __shared__ float sV[64][68];

    const float* Qp = Q + ((size_t)bh * SEQ + i) * HD + sl * 16;
    float4 q4[4];
#pragma unroll
    for (int d0 = 0; d0 < 4; ++d0) q4[d0] = ((const float4*)Qp)[d0];

    float4 acc[4];
#pragma unroll
    for (int d0 = 0; d0 < 4; ++d0) acc[d0] = make_float4(0.f, 0.f, 0.f, 0.f);
    float mrun = -INFINITY;
    float lrun = 0.0f;

    const int srow = t >> 4;        // 0..15
    const int scol = (t & 15) * 4;  // 0..60

    for (int jt = 0; jt < SEQ / 64; ++jt) {
        __syncthreads();
        const float* Kp = K + ((size_t)bh * SEQ + jt * 64) * HD;
        const float* Vp = V + ((size_t)bh * SEQ + jt * 64) * HD;
#pragma unroll
        for (int rr = 0; rr < 4; ++rr) {
            int row = rr * 16 + srow;
            *(float4*)&sK[row][scol] = *(const float4*)&Kp[(size_t)row * HD + scol];
            *(float4*)&sV[row][scol] = *(const float4*)&Vp[(size_t)row * HD + scol];
        }
        __syncthreads();

        for (int jc = 0; jc < 8; ++jc) {
            float s[8];
#pragma unroll
            for (int jj = 0; jj < 8; ++jj) {
                int j  = jc * 8 + jj;
                int jg = jt * 64 + j;
                float sc = 0.0f;
#pragma unroll
                for (int d0 = 0; d0 < 4; ++d0) {
                    float4 kv = *(const float4*)&sK[j][sl * 16 + d0 * 4];
                    sc = fmaf(q4[d0].x, kv.x,
                         fmaf(q4[d0].y, kv.y,
                         fmaf(q4[d0].z, kv.z,
                         fmaf(q4[d0].w, kv.w, sc))));
                }
                int rel = jg - i + 64;
                if (rel >= 0 && rel < RK) {
                    const float4* Ekp = (const float4*)&Ek[(size_t)rel * HD + sl * 16];
#pragma unroll
                    for (int d0 = 0; d0 < 4; ++d0) {
                        float4 ev = Ekp[d0];
                        sc = fmaf(q4[d0].x, ev.x,
                             fmaf(q4[d0].y, ev.y,
                             fmaf(q4[d0].z, ev.z,
                             fmaf(q4[d0].w, ev.w, sc))));
                    }
                }
                // sum the 4 slice-partials within the row group
                sc += __shfl_xor(sc, 1);
                sc += __shfl_xor(sc, 2);
                // attention mask term (reference: + (1-m)*finfo.min)
                sc += (1.0f - mask[b * SEQ + jg]) * FMIN;
                s[jj] = sc;
            }
            float cm = s[0];
#pragma unroll
            for (int jj = 1; jj < 8; ++jj) cm = fmaxf(cm, s[jj]);
            if (cm > mrun) {
                float f = __expf(mrun - cm);   // exp(-inf)=0 on first chunk
                lrun *= f;
#pragma unroll
                for (int d0 = 0; d0 < 4; ++d0) {
                    acc[d0].x *= f; acc[d0].y *= f; acc[d0].z *= f; acc[d0].w *= f;
                }
                mrun = cm;
            }
#pragma unroll
            for (int jj = 0; jj < 8; ++jj) {
                int j  = jc * 8 + jj;
                int jg = jt * 64 + j;
                float p = __expf(s[jj] - mrun);
                lrun += p;
#pragma unroll
                for (int d0 = 0; d0 < 4; ++d0) {
                    float4 vv = *(const float4*)&sV[j][sl * 16 + d0 * 4];
                    acc[d0].x = fmaf(p, vv.x, acc[d0].x);
                    acc[d0].y = fmaf(p, vv.y, acc[d0].y);
                    acc[d0].z = fmaf(p, vv.z, acc[d0].z);
                    acc[d0].w = fmaf(p, vv.w, acc[d0].w);
                }
                int rel = jg - i + 64;
                if (rel >= 0 && rel < RK) {
                    const float4* Evp = (const float4*)&Ev[(size_t)rel * HD + sl * 16];
#pragma unroll
                    for (int d0 = 0; d0 < 4; ++d0) {
                        float4 ev = Evp[d0];
                        acc[d0].x = fmaf(p, ev.x, acc[d0].x);
                        acc[d0].y = fmaf(p, ev.y, acc[d0].y);
                        acc[d0].z = fmaf(p, ev.z, acc[d0].z);
                        acc[d0].w = fmaf(p, ev.w, acc[d0].w);
                    }
                }
            }
        }
    }

    float inv = 1.0f / lrun;
    float* Op = out + ((size_t)(b * SEQ + i) * HDIM) + h * HD + sl * 16;
#pragma unroll
    for (int d0 = 0; d0 < 4; ++d0) {
        float4 o;
        o.x = acc[d0].x * inv; o.y = acc[d0].y * inv;
        o.z = acc[d0].z * inv; o.w = acc[d0].w * inv;
        ((float4*)Op)[d0] = o;
    }
}

extern "C" void kernel_launch(void* const* d_in, const int* in_sizes, int n_in,
                              void* d_out, int out_size, void* d_ws, size_t ws_size,
                              hipStream_t stream) {
    const float* X    = (const float*)d_in[0];
    const float* mask = (const float*)d_in[1];
    const float* Wq   = (const float*)d_in[2];
    const float* bq   = (const float*)d_in[3];
    const float* Wk   = (const float*)d_in[4];
    const float* bk   = (const float*)d_in[5];
    const float* Wv   = (const float*)d_in[6];
    const float* bv   = (const float*)d_in[7];
    const float* Ek   = (const float*)d_in[8];
    const float* Ev   = (const float*)d_in[9];
    float* out        = (float*)d_out;

    float* Qw = (float*)d_ws;
    size_t per = (size_t)BSZ * NH * SEQ * HD;   // 3,145,728 floats
    float* Kw = Qw + per;
    float* Vw = Kw + per;

    dim3 g1(4096 / BM, HDIM / BN, 3), b1(256);
    qkv_gemm_kernel<<<g1, b1, 0, stream>>>(X, Wq, bq, Wk, bk, Wv, bv, Qw, Kw, Vw);

    dim3 g2(SEQ / 64, NH, BSZ), b2(256);
    attn_kernel<<<g2, b2, 0, stream>>>(Qw, Kw, Vw, mask, Ek, Ev, out);
}

// Round 2
// 360.255 us; speedup vs baseline: 1.8021x; 1.8021x over previous
//
#include <hip/hip_runtime.h>
#include <hip/hip_bf16.h>
#include <math.h>

#define NH 12
#define SEQ 1024
#define HD 64
#define HDIM 768
#define BSZ 4
#define RK 129
#define FMIN -3.4028234663852886e38f

typedef __attribute__((ext_vector_type(8))) short bf16x8;
typedef __attribute__((ext_vector_type(4))) float f32x4;

__device__ inline short f2bf(float x) {
    union { __hip_bfloat16 h; short s; } u;
    u.h = __float2bfloat16(x);
    return u.s;
}
__device__ inline float bf2f(short s) {
    union { __hip_bfloat16 h; short t; } u;
    u.t = s;
    return __bfloat162float(u.h);
}

// ---------------- Kernel 1: fused QKV projection (fp32 tiled GEMM) ----------
#define BM 128
#define BN 128
#define BK 16

__global__ __launch_bounds__(256) void qkv_gemm_kernel(
    const float* __restrict__ X,
    const float* __restrict__ Wq, const float* __restrict__ bq,
    const float* __restrict__ Wk, const float* __restrict__ bk,
    const float* __restrict__ Wv, const float* __restrict__ bv,
    float* __restrict__ Qo, float* __restrict__ Ko, float* __restrict__ Vo)
{
    const int which = blockIdx.z;
    const float* __restrict__ W    = (which == 0) ? Wq : (which == 1) ? Wk : Wv;
    const float* __restrict__ bias = (which == 0) ? bq : (which == 1) ? bk : bv;
    float* __restrict__ Y          = (which == 0) ? Qo : (which == 1) ? Ko : Vo;

    __shared__ float sA[BK][BM + 4];
    __shared__ float sB[BK][BN + 4];

    const int t  = threadIdx.x;
    const int m0 = blockIdx.x * BM;
    const int n0 = blockIdx.y * BN;
    const int tx = t & 15;
    const int ty = t >> 4;

    float c[8][8];
#pragma unroll
    for (int i = 0; i < 8; ++i)
#pragma unroll
        for (int j = 0; j < 8; ++j) c[i][j] = 0.0f;

    const int arow = t >> 2;
    const int acol = (t & 3) * 4;
    const int brow = t >> 5;
    const int bcol = (t & 31) * 4;

    for (int k0 = 0; k0 < HDIM; k0 += BK) {
        __syncthreads();
#pragma unroll
        for (int rr = 0; rr < 2; ++rr) {
            float4 a = *(const float4*)&X[(size_t)(m0 + rr * 64 + arow) * HDIM + k0 + acol];
            sA[acol + 0][rr * 64 + arow] = a.x;
            sA[acol + 1][rr * 64 + arow] = a.y;
            sA[acol + 2][rr * 64 + arow] = a.z;
            sA[acol + 3][rr * 64 + arow] = a.w;
        }
#pragma unroll
        for (int rr = 0; rr < 2; ++rr) {
            *(float4*)&sB[rr * 8 + brow][bcol] =
                *(const float4*)&W[(size_t)(k0 + rr * 8 + brow) * HDIM + n0 + bcol];
        }
        __syncthreads();
#pragma unroll
        for (int kk = 0; kk < BK; ++kk) {
            float a[8], b[8];
            *(float4*)&a[0] = *(float4*)&sA[kk][ty * 8];
            *(float4*)&a[4] = *(float4*)&sA[kk][ty * 8 + 4];
            *(float4*)&b[0] = *(float4*)&sB[kk][tx * 4];
            *(float4*)&b[4] = *(float4*)&sB[kk][64 + tx * 4];
#pragma unroll
            for (int i = 0; i < 8; ++i)
#pragma unroll
                for (int j = 0; j < 8; ++j)
                    c[i][j] = fmaf(a[i], b[j], c[i][j]);
        }
    }

#pragma unroll
    for (int i = 0; i < 8; ++i) {
        int m  = m0 + ty * 8 + i;
        int bb = m >> 10;
        int ss = m & 1023;
#pragma unroll
        for (int jg = 0; jg < 2; ++jg) {
            int n  = n0 + jg * 64 + tx * 4;
            int hh = n >> 6;
            int dd = n & 63;
            float4 bv4 = *(const float4*)&bias[n];
            float4 o;
            o.x = c[i][jg * 4 + 0] + bv4.x;
            o.y = c[i][jg * 4 + 1] + bv4.y;
            o.z = c[i][jg * 4 + 2] + bv4.z;
            o.w = c[i][jg * 4 + 3] + bv4.w;
            size_t off = ((size_t)(bb * NH + hh) * SEQ + ss) * HD + dd;
            *(float4*)&Y[off] = o;
        }
    }
}

// ---------------- Kernel 2: MFMA flash attention with relative positions ---
// Block = 256 thr = 4 waves. Wave w owns q-rows [i0+16w, i0+16w+16).
// Static softmax (no max subtraction: |scores| < ~50 << 88 overflow limit).
// QK^T via 3-term bf16 split MFMA. Band key-scores gathered from per-wave
// P_pos = Q @ E_key^T (MFMA). Band probs scattered to LDS, folded in epilogue.
__global__ __launch_bounds__(256) void attn_mfma_kernel(
    const float* __restrict__ Q, const float* __restrict__ K,
    const float* __restrict__ V, const float* __restrict__ mask,
    const float* __restrict__ Ek, const float* __restrict__ Ev,
    float* __restrict__ out)
{
    __shared__ __align__(16) short sKhi[32][88];    // key tile hi, stride 176B
    __shared__ __align__(16) short sKlo[32][88];    // key tile lo
    __shared__ __align__(16) short sVT[64][40];     // V transposed [dim][key^swz]
    __shared__ __align__(16) short sPscr[4][16][40];// per-wave P scratch
    __shared__ __align__(16) short sPpos[4][16][132]; // per-wave Q@Ek^T
    __shared__ __align__(16) short sBand[4][16][132]; // per-wave band probs
    __shared__ float sMaskT[32];

    const int t  = threadIdx.x;
    const int w  = t >> 6;
    const int l  = t & 63;
    const int lq = l & 15;
    const int lg = l >> 4;
    const int b  = blockIdx.z;
    const int h  = blockIdx.y;
    const int i0 = blockIdx.x * 64;
    const int bh = b * NH + h;

    // zero the band buffers (cooperative; barrier before first use is in loop)
    for (int idx = t; idx < 4 * 16 * 132; idx += 256)
        (&sBand[0][0][0])[idx] = 0;

    // ---- Q fragments (A layout: row = lq, k = 8*lg + e, khalf kh) ----
    const int qrow = i0 + w * 16 + lq;
    const float* qp = Q + ((size_t)bh * SEQ + qrow) * HD;
    bf16x8 qhi[2], qlo[2];
#pragma unroll
    for (int kh = 0; kh < 2; ++kh) {
        float x[8];
        *(float4*)&x[0] = *(const float4*)&qp[kh * 32 + lg * 8];
        *(float4*)&x[4] = *(const float4*)&qp[kh * 32 + lg * 8 + 4];
#pragma unroll
        for (int e = 0; e < 8; ++e) {
            short hb = f2bf(x[e]);
            qhi[kh][e] = hb;
            qlo[kh][e] = f2bf(x[e] - bf2f(hb));
        }
    }

    // ---- P_pos = Q @ E_key^T  ([16 rows][129]) via MFMA ----
    {
        const int col = /* rel index */ 0;
        (void)col;
#pragma unroll
        for (int nt = 0; nt < 9; ++nt) {
            int cc = nt * 16 + lq;
            float msk = (cc < RK) ? 1.0f : 0.0f;
            int ccc = (cc < RK) ? cc : (RK - 1);
            bf16x8 eb[2];
#pragma unroll
            for (int kh = 0; kh < 2; ++kh) {
                float x[8];
                *(float4*)&x[0] = *(const float4*)&Ek[(size_t)ccc * HD + kh * 32 + lg * 8];
                *(float4*)&x[4] = *(const float4*)&Ek[(size_t)ccc * HD + kh * 32 + lg * 8 + 4];
#pragma unroll
                for (int e = 0; e < 8; ++e) eb[kh][e] = f2bf(x[e] * msk);
            }
            f32x4 pc = {0.f, 0.f, 0.f, 0.f};
            pc = __builtin_amdgcn_mfma_f32_16x16x32_bf16(qhi[0], eb[0], pc, 0, 0, 0);
            pc = __builtin_amdgcn_mfma_f32_16x16x32_bf16(qhi[1], eb[1], pc, 0, 0, 0);
            if (cc < 132) {
#pragma unroll
                for (int reg = 0; reg < 4; ++reg)
                    sPpos[w][lg * 4 + reg][cc] = f2bf(pc[reg]);
            }
        }
    }

    f32x4 acc[4];
#pragma unroll
    for (int nt = 0; nt < 4; ++nt) acc[nt] = (f32x4){0.f, 0.f, 0.f, 0.f};
    float lacc[4] = {0.f, 0.f, 0.f, 0.f};

    // ---- main loop over 32-key tiles ----
    for (int jt = 0; jt < SEQ / 32; ++jt) {
        __syncthreads();
        // stage K (hi/lo) and V^T (bf16) + mask terms
        {
            const int srow = t >> 3;
            const int sc0  = (t & 7) * 8;
            const float* kp = K + ((size_t)bh * SEQ + jt * 32 + srow) * HD + sc0;
            const float* vp = V + ((size_t)bh * SEQ + jt * 32 + srow) * HD + sc0;
            float kx[8], vx[8];
            *(float4*)&kx[0] = *(const float4*)&kp[0];
            *(float4*)&kx[4] = *(const float4*)&kp[4];
            *(float4*)&vx[0] = *(const float4*)&vp[0];
            *(float4*)&vx[4] = *(const float4*)&vp[4];
            bf16x8 khi8, klo8;
#pragma unroll
            for (int e = 0; e < 8; ++e) {
                short hb = f2bf(kx[e]);
                khi8[e] = hb;
                klo8[e] = f2bf(kx[e] - bf2f(hb));
            }
            *(bf16x8*)&sKhi[srow][sc0] = khi8;
            *(bf16x8*)&sKlo[srow][sc0] = klo8;
#pragma unroll
            for (int e = 0; e < 8; ++e) {
                int dim = sc0 + e;
                int swz = srow ^ (((dim >> 3) & 3) << 3);
                sVT[dim][swz] = f2bf(vx[e]);
            }
            if (t < 32)
                sMaskT[t] = (1.0f - mask[(size_t)b * SEQ + jt * 32 + t]) * FMIN;
        }
        __syncthreads();

        // scores for 2 column tiles of 16 keys
#pragma unroll
        for (int ct = 0; ct < 2; ++ct) {
            const int kc = ct * 16 + lq;
            bf16x8 bh0 = *(const bf16x8*)&sKhi[kc][lg * 8];
            bf16x8 bh1 = *(const bf16x8*)&sKhi[kc][32 + lg * 8];
            bf16x8 bl0 = *(const bf16x8*)&sKlo[kc][lg * 8];
            bf16x8 bl1 = *(const bf16x8*)&sKlo[kc][32 + lg * 8];
            f32x4 sc = {0.f, 0.f, 0.f, 0.f};
            sc = __builtin_amdgcn_mfma_f32_16x16x32_bf16(qhi[0], bh0, sc, 0, 0, 0);
            sc = __builtin_amdgcn_mfma_f32_16x16x32_bf16(qhi[1], bh1, sc, 0, 0, 0);
            sc = __builtin_amdgcn_mfma_f32_16x16x32_bf16(qlo[0], bh0, sc, 0, 0, 0);
            sc = __builtin_amdgcn_mfma_f32_16x16x32_bf16(qlo[1], bh1, sc, 0, 0, 0);
            sc = __builtin_amdgcn_mfma_f32_16x16x32_bf16(qhi[0], bl0, sc, 0, 0, 0);
            sc = __builtin_amdgcn_mfma_f32_16x16x32_bf16(qhi[1], bl1, sc, 0, 0, 0);
            const float mt = sMaskT[kc];
            const int jg = jt * 32 + kc;
#pragma unroll
            for (int reg = 0; reg < 4; ++reg) {
                int row = lg * 4 + reg;
                int rel = jg - (i0 + w * 16 + row) + 64;
                float s = sc[reg] + mt;
                bool inb = ((unsigned)rel < (unsigned)RK);
                if (inb) s += bf2f(sPpos[w][row][rel]);
                float p = __expf(s);
                lacc[reg] += p;
                short pb = f2bf(p);
                sPscr[w][row][kc] = pb;
                if (inb) sBand[w][row][rel] = pb;
            }
        }

        // PV: acc += P[16x32] @ V[32x64]
        bf16x8 pa = *(const bf16x8*)&sPscr[w][lq][lg * 8];
#pragma unroll
        for (int nt = 0; nt < 4; ++nt) {
            int dim = nt * 16 + lq;
            int ko  = (lg * 8) ^ ((((dim) >> 3) & 3) << 3);
            bf16x8 vb = *(const bf16x8*)&sVT[dim][ko];
            acc[nt] = __builtin_amdgcn_mfma_f32_16x16x32_bf16(pa, vb, acc[nt], 0, 0, 0);
        }
    }

    // ---- l reduction over the 16 key-columns lanes ----
    float linv[4];
#pragma unroll
    for (int reg = 0; reg < 4; ++reg) {
        float lr = lacc[reg];
        lr += __shfl_xor(lr, 1);
        lr += __shfl_xor(lr, 2);
        lr += __shfl_xor(lr, 4);
        lr += __shfl_xor(lr, 8);
        linv[reg] = 1.0f / lr;
    }

    // ---- band value term: acc += bandP @ E_val ----
    for (int r = 0; r < RK; ++r) {
        float pbv[4];
#pragma unroll
        for (int reg = 0; reg < 4; ++reg)
            pbv[reg] = bf2f(sBand[w][lg * 4 + reg][r]);
        const float* evp = Ev + (size_t)r * HD + lq;
        float e0 = evp[0], e1 = evp[16], e2 = evp[32], e3 = evp[48];
#pragma unroll
        for (int reg = 0; reg < 4; ++reg) {
            acc[0][reg] = fmaf(pbv[reg], e0, acc[0][reg]);
            acc[1][reg] = fmaf(pbv[reg], e1, acc[1][reg]);
            acc[2][reg] = fmaf(pbv[reg], e2, acc[2][reg]);
            acc[3][reg] = fmaf(pbv[reg], e3, acc[3][reg]);
        }
    }

    // ---- store [B,S,H] ----
#pragma unroll
    for (int nt = 0; nt < 4; ++nt) {
#pragma unroll
        for (int reg = 0; reg < 4; ++reg) {
            int qi = i0 + w * 16 + lg * 4 + reg;
            out[((size_t)b * SEQ + qi) * HDIM + h * HD + nt * 16 + lq] =
                acc[nt][reg] * linv[reg];
        }
    }
}

extern "C" void kernel_launch(void* const* d_in, const int* in_sizes, int n_in,
                              void* d_out, int out_size, void* d_ws, size_t ws_size,
                              hipStream_t stream) {
    const float* X    = (const float*)d_in[0];
    const float* mask = (const float*)d_in[1];
    const float* Wq   = (const float*)d_in[2];
    const float* bq   = (const float*)d_in[3];
    const float* Wk   = (const float*)d_in[4];
    const float* bk   = (const float*)d_in[5];
    const float* Wv   = (const float*)d_in[6];
    const float* bv   = (const float*)d_in[7];
    const float* Ek   = (const float*)d_in[8];
    const float* Ev   = (const float*)d_in[9];
    float* out        = (float*)d_out;

    float* Qw = (float*)d_ws;
    size_t per = (size_t)BSZ * NH * SEQ * HD;
    float* Kw = Qw + per;
    float* Vw = Kw + per;

    dim3 g1(4096 / BM, HDIM / BN, 3), b1(256);
    qkv_gemm_kernel<<<g1, b1, 0, stream>>>(X, Wq, bq, Wk, bk, Wv, bv, Qw, Kw, Vw);

    dim3 g2(SEQ / 64, NH, BSZ), b2(256);
    attn_mfma_kernel<<<g2, b2, 0, stream>>>(Qw, Kw, Vw, mask, Ek, Ev, out);
}

// Round 3
// 112.541 us; speedup vs baseline: 5.7686x; 3.2011x over previous
//
#include <hip/hip_runtime.h>
#include <hip/hip_bf16.h>
#include <math.h>

#define NH 12
#define SEQ 1024
#define HD 64
#define HDIM 768
#define BSZ 4
#define RK 129
#define FMIN -3.4028234663852886e38f

typedef __attribute__((ext_vector_type(8))) short short8;
typedef __attribute__((ext_vector_type(8))) _Float16 f16x8;
typedef __attribute__((ext_vector_type(4))) float f32x4;

__device__ inline short f2bf(float x) {
    union { __hip_bfloat16 h; short s; } u;
    u.h = __float2bfloat16(x);
    return u.s;
}

__device__ inline void async_load16(void* lds, const void* g) {
    __builtin_amdgcn_global_load_lds(
        (const __attribute__((address_space(1))) unsigned int*)g,
        (__attribute__((address_space(3))) unsigned int*)lds, 16, 0, 0);
}

// ---------------- Kernel 0a: f32 -> f16 convert (X and E_key) --------------
#define NXCHUNK 393216   // 4096*768/8
#define NECHUNK 1032     // 129*64/8
__global__ __launch_bounds__(256) void convert_f16_kernel(
    const float* __restrict__ X, const float* __restrict__ Ek,
    _Float16* __restrict__ Xh, _Float16* __restrict__ Ekh)
{
    int idx = blockIdx.x * 256 + threadIdx.x;
    const float* src;
    _Float16* dst;
    if (idx < NXCHUNK) {
        src = X; dst = Xh;
    } else if (idx < NXCHUNK + NECHUNK) {
        idx -= NXCHUNK; src = Ek; dst = Ekh;
    } else return;
    float4 a = ((const float4*)src)[idx * 2];
    float4 b = ((const float4*)src)[idx * 2 + 1];
    f16x8 o;
    o[0] = (_Float16)a.x; o[1] = (_Float16)a.y; o[2] = (_Float16)a.z; o[3] = (_Float16)a.w;
    o[4] = (_Float16)b.x; o[5] = (_Float16)b.y; o[6] = (_Float16)b.z; o[7] = (_Float16)b.w;
    ((f16x8*)dst)[idx] = o;
}

// ---------------- Kernel 0b: W[k][n] f32 -> Wt[n][k] f16 (transpose) -------
__global__ __launch_bounds__(256) void transpose_w_kernel(
    const float* __restrict__ Wq, const float* __restrict__ Wk, const float* __restrict__ Wv,
    _Float16* __restrict__ Wtq, _Float16* __restrict__ Wtk, _Float16* __restrict__ Wtv)
{
    const int z = blockIdx.z;
    const float* __restrict__ W = (z == 0) ? Wq : (z == 1) ? Wk : Wv;
    _Float16* __restrict__ Wt   = (z == 0) ? Wtq : (z == 1) ? Wtk : Wtv;

    __shared__ float sT[64][65];   // sT[n][k]
    const int t  = threadIdx.x;
    const int k0 = blockIdx.x * 64;
    const int n0 = blockIdx.y * 64;

    const int c  = (t & 15) * 4;
    const int kr = t >> 4;
#pragma unroll
    for (int rr = 0; rr < 4; ++rr) {
        float4 v = *(const float4*)&W[(size_t)(k0 + kr + rr * 16) * HDIM + n0 + c];
        sT[c + 0][kr + rr * 16] = v.x;
        sT[c + 1][kr + rr * 16] = v.y;
        sT[c + 2][kr + rr * 16] = v.z;
        sT[c + 3][kr + rr * 16] = v.w;
    }
    __syncthreads();
    const int rn = t >> 2;
    const int ck = (t & 3) * 16;
#pragma unroll
    for (int g = 0; g < 2; ++g) {
        f16x8 o;
#pragma unroll
        for (int e = 0; e < 8; ++e) o[e] = (_Float16)sT[rn][ck + g * 8 + e];
        *(f16x8*)&Wt[(size_t)(n0 + rn) * HDIM + k0 + ck + g * 8] = o;
    }
}

// ---------------- Kernel 1: QKV projection via f16 MFMA --------------------
// C[m][n] = sum_k Xh[m][k] * Wt[n][k] + bias[n].  128x128 tile, BK=64,
// global_load_lds staging with XOR-swizzled source + swizzled ds_read_b128.
__global__ __launch_bounds__(256) void qkv_mfma_kernel(
    const _Float16* __restrict__ Xh,
    const _Float16* __restrict__ Wtq, const _Float16* __restrict__ Wtk, const _Float16* __restrict__ Wtv,
    const float* __restrict__ bq, const float* __restrict__ bk, const float* __restrict__ bv,
    _Float16* __restrict__ Qo, _Float16* __restrict__ Ko, short* __restrict__ Vo)
{
    int bid = blockIdx.x;
    bid = (bid & 7) * 72 + (bid >> 3);          // XCD swizzle (576 = 8*72)
    const int which = bid / 192;
    const int rem   = bid % 192;
    const int n0    = (rem / 32) * 128;
    const int m0    = (rem % 32) * 128;
    const _Float16* __restrict__ Wt = (which == 0) ? Wtq : (which == 1) ? Wtk : Wtv;
    const float* __restrict__ bias  = (which == 0) ? bq : (which == 1) ? bk : bv;

    __shared__ __align__(16) _Float16 sA[128 * 64];
    __shared__ __align__(16) _Float16 sB[128 * 64];

    const int t  = threadIdx.x;
    const int w  = t >> 6, l = t & 63;
    const int lq = l & 15, lg = l >> 4;
    const int wr = w >> 1, wc = w & 1;

    f32x4 acc[4][4];
#pragma unroll
    for (int i = 0; i < 4; ++i)
#pragma unroll
        for (int j = 0; j < 4; ++j) acc[i][j] = (f32x4){0.f, 0.f, 0.f, 0.f};

    for (int k0 = 0; k0 < HDIM; k0 += 64) {
        __syncthreads();
#pragma unroll
        for (int r = 0; r < 4; ++r) {
            const int cib = r * 256 + w * 64;   // wave-uniform chunk base
            const int ci  = cib + l;
            const int row = ci >> 3, cr = ci & 7;
            const int lc  = cr ^ (row & 7);     // pre-swizzled source chunk
            async_load16(&sA[(size_t)cib * 8],
                         &Xh[(size_t)(m0 + row) * HDIM + k0 + lc * 8]);
            async_load16(&sB[(size_t)cib * 8],
                         &Wt[(size_t)(n0 + row) * HDIM + k0 + lc * 8]);
        }
        __syncthreads();

        f16x8 af[4][2], bf[4][2];
#pragma unroll
        for (int i = 0; i < 4; ++i) {
#pragma unroll
            for (int ks = 0; ks < 2; ++ks) {
                int ra = wr * 64 + i * 16 + lq;
                af[i][ks] = *(const f16x8*)((const char*)sA +
                            ra * 128 + ((ks * 64 + lg * 16) ^ ((ra & 7) << 4)));
                int rb = wc * 64 + i * 16 + lq;
                bf[i][ks] = *(const f16x8*)((const char*)sB +
                            rb * 128 + ((ks * 64 + lg * 16) ^ ((rb & 7) << 4)));
            }
        }
#pragma unroll
        for (int i = 0; i < 4; ++i)
#pragma unroll
            for (int j = 0; j < 4; ++j) {
                acc[i][j] = __builtin_amdgcn_mfma_f32_16x16x32_f16(af[i][0], bf[j][0], acc[i][j], 0, 0, 0);
                acc[i][j] = __builtin_amdgcn_mfma_f32_16x16x32_f16(af[i][1], bf[j][1], acc[i][j], 0, 0, 0);
            }
    }

    _Float16* __restrict__ Yh = (which == 0) ? Qo : Ko;
#pragma unroll
    for (int i = 0; i < 4; ++i) {
        const int mb = m0 + wr * 64 + i * 16 + lg * 4;
#pragma unroll
        for (int j = 0; j < 4; ++j) {
            const int n  = n0 + wc * 64 + j * 16 + lq;
            const float bv4 = bias[n];
            const int hh = n >> 6, dd = n & 63;
#pragma unroll
            for (int reg = 0; reg < 4; ++reg) {
                const int mm = mb + reg;
                const int bb = mm >> 10, ss = mm & 1023;
                const size_t off = ((size_t)(bb * NH + hh) * SEQ + ss) * HD + dd;
                const float val = acc[i][j][reg] + bv4;
                if (which == 2) Vo[off] = f2bf(val);
                else            Yh[off] = (_Float16)val;
            }
        }
    }
}

// ---------------- Kernel 2: MFMA flash attention with relative positions ---
__global__ __launch_bounds__(256) void attn_mfma_kernel(
    const _Float16* __restrict__ Q, const _Float16* __restrict__ K,
    const short* __restrict__ V, const float* __restrict__ mask,
    const _Float16* __restrict__ Ekh, const float* __restrict__ Ev,
    float* __restrict__ out)
{
    __shared__ __align__(16) _Float16 sK[32][72];
    __shared__ __align__(16) short sVT[64][40];        // bf16 bits, transposed
    __shared__ __align__(16) short sPscr[4][16][40];   // bf16 probs
    __shared__ __align__(16) _Float16 sPpos[4][16][132];
    __shared__ __align__(16) short sBand[4][16][132];  // bf16 band probs
    __shared__ float sMaskT[32];

    const int t  = threadIdx.x;
    const int w  = t >> 6;
    const int l  = t & 63;
    const int lq = l & 15;
    const int lg = l >> 4;
    const int b  = blockIdx.z;
    const int h  = blockIdx.y;
    const int i0 = blockIdx.x * 64;
    const int bh = b * NH + h;

    for (int idx = t; idx < 4 * 16 * 132; idx += 256)
        (&sBand[0][0][0])[idx] = 0;

    const int qrow = i0 + w * 16 + lq;
    const _Float16* qp = Q + ((size_t)bh * SEQ + qrow) * HD;
    f16x8 qf[2];
    qf[0] = *(const f16x8*)&qp[lg * 8];
    qf[1] = *(const f16x8*)&qp[32 + lg * 8];

    // P_pos = Q @ E_key^T
#pragma unroll
    for (int nt = 0; nt < 9; ++nt) {
        int cc = nt * 16 + lq;
        f16x8 eb0 = {0, 0, 0, 0, 0, 0, 0, 0};
        f16x8 eb1 = {0, 0, 0, 0, 0, 0, 0, 0};
        if (cc < RK) {
            eb0 = *(const f16x8*)&Ekh[(size_t)cc * HD + lg * 8];
            eb1 = *(const f16x8*)&Ekh[(size_t)cc * HD + 32 + lg * 8];
        }
        f32x4 pc = {0.f, 0.f, 0.f, 0.f};
        pc = __builtin_amdgcn_mfma_f32_16x16x32_f16(qf[0], eb0, pc, 0, 0, 0);
        pc = __builtin_amdgcn_mfma_f32_16x16x32_f16(qf[1], eb1, pc, 0, 0, 0);
        if (cc < 132) {
#pragma unroll
            for (int reg = 0; reg < 4; ++reg)
                sPpos[w][lg * 4 + reg][cc] = (_Float16)pc[reg];
        }
    }

    f32x4 acc[4];
#pragma unroll
    for (int nt = 0; nt < 4; ++nt) acc[nt] = (f32x4){0.f, 0.f, 0.f, 0.f};
    float lacc[4] = {0.f, 0.f, 0.f, 0.f};

    for (int jt = 0; jt < SEQ / 32; ++jt) {
        __syncthreads();
        {
            const int row = t >> 3, c8 = (t & 7) * 8;
            *(f16x8*)&sK[row][c8] =
                *(const f16x8*)&K[((size_t)bh * SEQ + jt * 32 + row) * HD + c8];
            short8 v8 = *(const short8*)&V[((size_t)bh * SEQ + jt * 32 + row) * HD + c8];
#pragma unroll
            for (int e = 0; e < 8; ++e) {
                int dim = c8 + e;
                int swz = row ^ (((dim >> 3) & 3) << 3);
                sVT[dim][swz] = v8[e];
            }
            if (t < 32)
                sMaskT[t] = (1.0f - mask[(size_t)b * SEQ + jt * 32 + t]) * FMIN;
        }
        __syncthreads();

#pragma unroll
        for (int ct = 0; ct < 2; ++ct) {
            const int kc = ct * 16 + lq;
            f16x8 kb0 = *(const f16x8*)&sK[kc][lg * 8];
            f16x8 kb1 = *(const f16x8*)&sK[kc][32 + lg * 8];
            f32x4 sc = {0.f, 0.f, 0.f, 0.f};
            sc = __builtin_amdgcn_mfma_f32_16x16x32_f16(qf[0], kb0, sc, 0, 0, 0);
            sc = __builtin_amdgcn_mfma_f32_16x16x32_f16(qf[1], kb1, sc, 0, 0, 0);
            const float mt = sMaskT[kc];
            const int jg = jt * 32 + kc;
#pragma unroll
            for (int reg = 0; reg < 4; ++reg) {
                int row = lg * 4 + reg;
                int rel = jg - (i0 + w * 16 + row) + 64;
                float s = sc[reg] + mt;
                bool inb = ((unsigned)rel < (unsigned)RK);
                if (inb) s += (float)sPpos[w][row][rel];
                float p = __expf(s);
                lacc[reg] += p;
                short pb = f2bf(p);
                sPscr[w][row][kc] = pb;
                if (inb) sBand[w][row][rel] = pb;
            }
        }

        short8 pa = *(const short8*)&sPscr[w][lq][lg * 8];
#pragma unroll
        for (int nt = 0; nt < 4; ++nt) {
            int dim = nt * 16 + lq;
            int ko  = (lg * 8) ^ ((((dim) >> 3) & 3) << 3);
            short8 vb = *(const short8*)&sVT[dim][ko];
            acc[nt] = __builtin_amdgcn_mfma_f32_16x16x32_bf16(pa, vb, acc[nt], 0, 0, 0);
        }
    }

    float linv[4];
#pragma unroll
    for (int reg = 0; reg < 4; ++reg) {
        float lr = lacc[reg];
        lr += __shfl_xor(lr, 1);
        lr += __shfl_xor(lr, 2);
        lr += __shfl_xor(lr, 4);
        lr += __shfl_xor(lr, 8);
        linv[reg] = 1.0f / lr;
    }

    for (int r = 0; r < RK; ++r) {
        float pbv[4];
#pragma unroll
        for (int reg = 0; reg < 4; ++reg) {
            union { __hip_bfloat16 h; short s; } u;
            u.s = sBand[w][lg * 4 + reg][r];
            pbv[reg] = __bfloat162float(u.h);
        }
        const float* evp = Ev + (size_t)r * HD + lq;
        float e0 = evp[0], e1 = evp[16], e2 = evp[32], e3 = evp[48];
#pragma unroll
        for (int reg = 0; reg < 4; ++reg) {
            acc[0][reg] = fmaf(pbv[reg], e0, acc[0][reg]);
            acc[1][reg] = fmaf(pbv[reg], e1, acc[1][reg]);
            acc[2][reg] = fmaf(pbv[reg], e2, acc[2][reg]);
            acc[3][reg] = fmaf(pbv[reg], e3, acc[3][reg]);
        }
    }

#pragma unroll
    for (int nt = 0; nt < 4; ++nt) {
#pragma unroll
        for (int reg = 0; reg < 4; ++reg) {
            int qi = i0 + w * 16 + lg * 4 + reg;
            out[((size_t)b * SEQ + qi) * HDIM + h * HD + nt * 16 + lq] =
                acc[nt][reg] * linv[reg];
        }
    }
}

extern "C" void kernel_launch(void* const* d_in, const int* in_sizes, int n_in,
                              void* d_out, int out_size, void* d_ws, size_t ws_size,
                              hipStream_t stream) {
    const float* X    = (const float*)d_in[0];
    const float* mask = (const float*)d_in[1];
    const float* Wq   = (const float*)d_in[2];
    const float* bq   = (const float*)d_in[3];
    const float* Wk   = (const float*)d_in[4];
    const float* bk   = (const float*)d_in[5];
    const float* Wv   = (const float*)d_in[6];
    const float* bv   = (const float*)d_in[7];
    const float* Ek   = (const float*)d_in[8];
    const float* Ev   = (const float*)d_in[9];
    float* out        = (float*)d_out;

    char* ws = (char*)d_ws;
    const size_t SZ_QKV = (size_t)BSZ * NH * SEQ * HD * 2;   // 6,291,456 B each
    const size_t SZ_W   = (size_t)HDIM * HDIM * 2;           // 1,179,648 B each
    _Float16* Qh  = (_Float16*)(ws);
    _Float16* Kh  = (_Float16*)(ws + SZ_QKV);
    short*    Vb  = (short*)   (ws + 2 * SZ_QKV);
    _Float16* Xh  = (_Float16*)(ws + 3 * SZ_QKV);
    _Float16* Wtq = (_Float16*)(ws + 4 * SZ_QKV);
    _Float16* Wtk = (_Float16*)(ws + 4 * SZ_QKV + SZ_W);
    _Float16* Wtv = (_Float16*)(ws + 4 * SZ_QKV + 2 * SZ_W);
    _Float16* Ekh = (_Float16*)(ws + 4 * SZ_QKV + 3 * SZ_W);

    convert_f16_kernel<<<(NXCHUNK + NECHUNK + 255) / 256, 256, 0, stream>>>(X, Ek, Xh, Ekh);
    transpose_w_kernel<<<dim3(12, 12, 3), 256, 0, stream>>>(Wq, Wk, Wv, Wtq, Wtk, Wtv);
    qkv_mfma_kernel<<<576, 256, 0, stream>>>(Xh, Wtq, Wtk, Wtv, bq, bk, bv, Qh, Kh, Vb);
    attn_mfma_kernel<<<dim3(SEQ / 64, NH, BSZ), 256, 0, stream>>>(Qh, Kh, Vb, mask, Ekh, Ev, out);
}

// Round 4
// 98.210 us; speedup vs baseline: 6.6103x; 1.1459x over previous
//
#include <hip/hip_runtime.h>
#include <hip/hip_bf16.h>
#include <math.h>

#define NH 12
#define SEQ 1024
#define HD 64
#define HDIM 768
#define BSZ 4
#define RK 129
#define FMIN -3.4028234663852886e38f

typedef __attribute__((ext_vector_type(8))) short short8;
typedef __attribute__((ext_vector_type(8))) _Float16 f16x8;
typedef __attribute__((ext_vector_type(4))) float f32x4;

__device__ inline short f2bf(float x) {
    union { __hip_bfloat16 h; short s; } u;
    u.h = __float2bfloat16(x);
    return u.s;
}

__device__ inline void async_load16(void* lds, const void* g) {
    __builtin_amdgcn_global_load_lds(
        (const __attribute__((address_space(1))) unsigned int*)g,
        (__attribute__((address_space(3))) unsigned int*)lds, 16, 0, 0);
}

// ---------------- Kernel 0a: f32 -> f16 convert (X, E_key) + Evt build -----
#define NXCHUNK 393216   // 4096*768/8
#define NECHUNK 1032     // 129*64/8
#define NEVCHUNK 1280    // 64*160/8  (Evt: Ev transposed -> bf16, zero-padded)
__global__ __launch_bounds__(256) void convert_f16_kernel(
    const float* __restrict__ X, const float* __restrict__ Ek,
    const float* __restrict__ Ev,
    _Float16* __restrict__ Xh, _Float16* __restrict__ Ekh,
    short* __restrict__ Evt)
{
    int idx = blockIdx.x * 256 + threadIdx.x;
    if (idx < NXCHUNK + NECHUNK) {
        const float* src;
        _Float16* dst;
        if (idx < NXCHUNK) { src = X; dst = Xh; }
        else { idx -= NXCHUNK; src = Ek; dst = Ekh; }
        float4 a = ((const float4*)src)[idx * 2];
        float4 b = ((const float4*)src)[idx * 2 + 1];
        f16x8 o;
        o[0] = (_Float16)a.x; o[1] = (_Float16)a.y; o[2] = (_Float16)a.z; o[3] = (_Float16)a.w;
        o[4] = (_Float16)b.x; o[5] = (_Float16)b.y; o[6] = (_Float16)b.z; o[7] = (_Float16)b.w;
        ((f16x8*)dst)[idx] = o;
    } else if (idx < NXCHUNK + NECHUNK + NEVCHUNK) {
        idx -= NXCHUNK + NECHUNK;
        const int dim = idx / 20;          // 160/8 = 20 chunks per dim
        const int r0  = (idx % 20) * 8;
        short8 o;
#pragma unroll
        for (int e = 0; e < 8; ++e) {
            int rel = r0 + e;
            float v = (rel < RK) ? Ev[(size_t)rel * HD + dim] : 0.0f;
            o[e] = f2bf(v);
        }
        *(short8*)&Evt[(size_t)dim * 160 + r0] = o;
    }
}

// ---------------- Kernel 0b: W[k][n] f32 -> Wt[n][k] f16 (transpose) -------
__global__ __launch_bounds__(256) void transpose_w_kernel(
    const float* __restrict__ Wq, const float* __restrict__ Wk, const float* __restrict__ Wv,
    _Float16* __restrict__ Wtq, _Float16* __restrict__ Wtk, _Float16* __restrict__ Wtv)
{
    const int z = blockIdx.z;
    const float* __restrict__ W = (z == 0) ? Wq : (z == 1) ? Wk : Wv;
    _Float16* __restrict__ Wt   = (z == 0) ? Wtq : (z == 1) ? Wtk : Wtv;

    __shared__ float sT[64][65];
    const int t  = threadIdx.x;
    const int k0 = blockIdx.x * 64;
    const int n0 = blockIdx.y * 64;

    const int c  = (t & 15) * 4;
    const int kr = t >> 4;
#pragma unroll
    for (int rr = 0; rr < 4; ++rr) {
        float4 v = *(const float4*)&W[(size_t)(k0 + kr + rr * 16) * HDIM + n0 + c];
        sT[c + 0][kr + rr * 16] = v.x;
        sT[c + 1][kr + rr * 16] = v.y;
        sT[c + 2][kr + rr * 16] = v.z;
        sT[c + 3][kr + rr * 16] = v.w;
    }
    __syncthreads();
    const int rn = t >> 2;
    const int ck = (t & 3) * 16;
#pragma unroll
    for (int g = 0; g < 2; ++g) {
        f16x8 o;
#pragma unroll
        for (int e = 0; e < 8; ++e) o[e] = (_Float16)sT[rn][ck + g * 8 + e];
        *(f16x8*)&Wt[(size_t)(n0 + rn) * HDIM + k0 + ck + g * 8] = o;
    }
}

// ---------------- Kernel 1: QKV projection via f16 MFMA --------------------
__global__ __launch_bounds__(256) void qkv_mfma_kernel(
    const _Float16* __restrict__ Xh,
    const _Float16* __restrict__ Wtq, const _Float16* __restrict__ Wtk, const _Float16* __restrict__ Wtv,
    const float* __restrict__ bq, const float* __restrict__ bk, const float* __restrict__ bv,
    _Float16* __restrict__ Qo, _Float16* __restrict__ Ko, short* __restrict__ Vo)
{
    int bid = blockIdx.x;
    bid = (bid & 7) * 72 + (bid >> 3);          // XCD swizzle (576 = 8*72)
    const int which = bid / 192;
    const int rem   = bid % 192;
    const int n0    = (rem / 32) * 128;
    const int m0    = (rem % 32) * 128;
    const _Float16* __restrict__ Wt = (which == 0) ? Wtq : (which == 1) ? Wtk : Wtv;
    const float* __restrict__ bias  = (which == 0) ? bq : (which == 1) ? bk : bv;

    __shared__ __align__(16) _Float16 sA[128 * 64];
    __shared__ __align__(16) _Float16 sB[128 * 64];

    const int t  = threadIdx.x;
    const int w  = t >> 6, l = t & 63;
    const int lq = l & 15, lg = l >> 4;
    const int wr = w >> 1, wc = w & 1;

    f32x4 acc[4][4];
#pragma unroll
    for (int i = 0; i < 4; ++i)
#pragma unroll
        for (int j = 0; j < 4; ++j) acc[i][j] = (f32x4){0.f, 0.f, 0.f, 0.f};

    for (int k0 = 0; k0 < HDIM; k0 += 64) {
        __syncthreads();
#pragma unroll
        for (int r = 0; r < 4; ++r) {
            const int cib = r * 256 + w * 64;
            const int ci  = cib + l;
            const int row = ci >> 3, cr = ci & 7;
            const int lc  = cr ^ (row & 7);
            async_load16(&sA[(size_t)cib * 8],
                         &Xh[(size_t)(m0 + row) * HDIM + k0 + lc * 8]);
            async_load16(&sB[(size_t)cib * 8],
                         &Wt[(size_t)(n0 + row) * HDIM + k0 + lc * 8]);
        }
        __syncthreads();

        f16x8 af[4][2], bf[4][2];
#pragma unroll
        for (int i = 0; i < 4; ++i) {
#pragma unroll
            for (int ks = 0; ks < 2; ++ks) {
                int ra = wr * 64 + i * 16 + lq;
                af[i][ks] = *(const f16x8*)((const char*)sA +
                            ra * 128 + ((ks * 64 + lg * 16) ^ ((ra & 7) << 4)));
                int rb = wc * 64 + i * 16 + lq;
                bf[i][ks] = *(const f16x8*)((const char*)sB +
                            rb * 128 + ((ks * 64 + lg * 16) ^ ((rb & 7) << 4)));
            }
        }
#pragma unroll
        for (int i = 0; i < 4; ++i)
#pragma unroll
            for (int j = 0; j < 4; ++j) {
                acc[i][j] = __builtin_amdgcn_mfma_f32_16x16x32_f16(af[i][0], bf[j][0], acc[i][j], 0, 0, 0);
                acc[i][j] = __builtin_amdgcn_mfma_f32_16x16x32_f16(af[i][1], bf[j][1], acc[i][j], 0, 0, 0);
            }
    }

    _Float16* __restrict__ Yh = (which == 0) ? Qo : Ko;
#pragma unroll
    for (int i = 0; i < 4; ++i) {
        const int mb = m0 + wr * 64 + i * 16 + lg * 4;
#pragma unroll
        for (int j = 0; j < 4; ++j) {
            const int n  = n0 + wc * 64 + j * 16 + lq;
            const float bv4 = bias[n];
            const int hh = n >> 6, dd = n & 63;
#pragma unroll
            for (int reg = 0; reg < 4; ++reg) {
                const int mm = mb + reg;
                const int bb = mm >> 10, ss = mm & 1023;
                const size_t off = ((size_t)(bb * NH + hh) * SEQ + ss) * HD + dd;
                const float val = acc[i][j][reg] + bv4;
                if (which == 2) Vo[off] = f2bf(val);
                else            Yh[off] = (_Float16)val;
            }
        }
    }
}

// ---------------- Kernel 2: MFMA flash attention with relative positions ---
__global__ __launch_bounds__(256) void attn_mfma_kernel(
    const _Float16* __restrict__ Q, const _Float16* __restrict__ K,
    const short* __restrict__ V, const float* __restrict__ mask,
    const _Float16* __restrict__ Ekh, const short* __restrict__ Evt,
    float* __restrict__ out)
{
    __shared__ __align__(16) _Float16 sK[32][72];
    __shared__ __align__(16) short sVT[64][40];        // bf16, transposed+swz
    __shared__ __align__(16) short sPscr[4][16][40];   // bf16 probs (PV A-frag)
    __shared__ __align__(16) _Float16 sPpos[4][16][132];
    __shared__ __align__(16) short sBand[4][16][168];  // bf16 band probs, rel-aligned
    __shared__ float sMaskT[32];

    const int t  = threadIdx.x;
    const int w  = t >> 6;
    const int l  = t & 63;
    const int lq = l & 15;
    const int lg = l >> 4;
    const int b  = blockIdx.z;
    const int h  = blockIdx.y;
    const int i0 = blockIdx.x * 64;
    const int bh = b * NH + h;

    // zero band buffer (4*16*168 shorts = 1344 short8 chunks)
    {
        short8 z8 = {0, 0, 0, 0, 0, 0, 0, 0};
        short8* p = (short8*)&sBand[0][0][0];
        for (int idx = t; idx < 1344; idx += 256) p[idx] = z8;
    }

    const int qrow = i0 + w * 16 + lq;
    const _Float16* qp = Q + ((size_t)bh * SEQ + qrow) * HD;
    f16x8 qf[2];
    qf[0] = *(const f16x8*)&qp[lg * 8];
    qf[1] = *(const f16x8*)&qp[32 + lg * 8];

    // P_pos = Q @ E_key^T
#pragma unroll
    for (int nt = 0; nt < 9; ++nt) {
        int cc = nt * 16 + lq;
        f16x8 eb0 = {0, 0, 0, 0, 0, 0, 0, 0};
        f16x8 eb1 = {0, 0, 0, 0, 0, 0, 0, 0};
        if (cc < RK) {
            eb0 = *(const f16x8*)&Ekh[(size_t)cc * HD + lg * 8];
            eb1 = *(const f16x8*)&Ekh[(size_t)cc * HD + 32 + lg * 8];
        }
        f32x4 pc = {0.f, 0.f, 0.f, 0.f};
        pc = __builtin_amdgcn_mfma_f32_16x16x32_f16(qf[0], eb0, pc, 0, 0, 0);
        pc = __builtin_amdgcn_mfma_f32_16x16x32_f16(qf[1], eb1, pc, 0, 0, 0);
        if (cc < 132) {
#pragma unroll
            for (int reg = 0; reg < 4; ++reg)
                sPpos[w][lg * 4 + reg][cc] = (_Float16)pc[reg];
        }
    }

    f32x4 acc[4];
#pragma unroll
    for (int nt = 0; nt < 4; ++nt) acc[nt] = (f32x4){0.f, 0.f, 0.f, 0.f};
    float lacc[4] = {0.f, 0.f, 0.f, 0.f};

    for (int jt = 0; jt < SEQ / 32; ++jt) {
        __syncthreads();
        {
            const int row = t >> 3, c8 = (t & 7) * 8;
            *(f16x8*)&sK[row][c8] =
                *(const f16x8*)&K[((size_t)bh * SEQ + jt * 32 + row) * HD + c8];
            short8 v8 = *(const short8*)&V[((size_t)bh * SEQ + jt * 32 + row) * HD + c8];
#pragma unroll
            for (int e = 0; e < 8; ++e) {
                int dim = c8 + e;
                int swz = row ^ (((dim >> 3) & 3) << 3);
                sVT[dim][swz] = v8[e];
            }
            if (t < 32)
                sMaskT[t] = (1.0f - mask[(size_t)b * SEQ + jt * 32 + t]) * FMIN;
        }
        __syncthreads();

#pragma unroll
        for (int ct = 0; ct < 2; ++ct) {
            const int kc = ct * 16 + lq;
            f16x8 kb0 = *(const f16x8*)&sK[kc][lg * 8];
            f16x8 kb1 = *(const f16x8*)&sK[kc][32 + lg * 8];
            f32x4 sc = {0.f, 0.f, 0.f, 0.f};
            sc = __builtin_amdgcn_mfma_f32_16x16x32_f16(qf[0], kb0, sc, 0, 0, 0);
            sc = __builtin_amdgcn_mfma_f32_16x16x32_f16(qf[1], kb1, sc, 0, 0, 0);
            const float mt = sMaskT[kc];
            const int jg = jt * 32 + kc;
#pragma unroll
            for (int reg = 0; reg < 4; ++reg) {
                int row = lg * 4 + reg;
                int rel = jg - (i0 + w * 16 + row) + 64;
                float s = sc[reg] + mt;
                bool inb = ((unsigned)rel < (unsigned)RK);
                if (inb) s += (float)sPpos[w][row][rel];
                float p = __expf(s);
                lacc[reg] += p;
                short pb = f2bf(p);
                sPscr[w][row][kc] = pb;
                if (inb) sBand[w][row][rel] = pb;
            }
        }

        short8 pa = *(const short8*)&sPscr[w][lq][lg * 8];
#pragma unroll
        for (int nt = 0; nt < 4; ++nt) {
            int dim = nt * 16 + lq;
            int ko  = (lg * 8) ^ ((((dim) >> 3) & 3) << 3);
            short8 vb = *(const short8*)&sVT[dim][ko];
            acc[nt] = __builtin_amdgcn_mfma_f32_16x16x32_bf16(pa, vb, acc[nt], 0, 0, 0);
        }
    }

    float linv[4];
#pragma unroll
    for (int reg = 0; reg < 4; ++reg) {
        float lr = lacc[reg];
        lr += __shfl_xor(lr, 1);
        lr += __shfl_xor(lr, 2);
        lr += __shfl_xor(lr, 4);
        lr += __shfl_xor(lr, 8);
        linv[reg] = 1.0f / lr;
    }

    // band value term via MFMA: acc[nt] += bandP[16x160] @ Evt^T[160x64]
    short8 bandA[5];
#pragma unroll
    for (int ks = 0; ks < 5; ++ks)
        bandA[ks] = *(const short8*)&sBand[w][lq][ks * 32 + lg * 8];
#pragma unroll
    for (int nt = 0; nt < 4; ++nt) {
#pragma unroll
        for (int ks = 0; ks < 5; ++ks) {
            short8 eb = *(const short8*)&Evt[(size_t)(nt * 16 + lq) * 160 + ks * 32 + lg * 8];
            acc[nt] = __builtin_amdgcn_mfma_f32_16x16x32_bf16(bandA[ks], eb, acc[nt], 0, 0, 0);
        }
    }

#pragma unroll
    for (int nt = 0; nt < 4; ++nt) {
#pragma unroll
        for (int reg = 0; reg < 4; ++reg) {
            int qi = i0 + w * 16 + lg * 4 + reg;
            out[((size_t)b * SEQ + qi) * HDIM + h * HD + nt * 16 + lq] =
                acc[nt][reg] * linv[reg];
        }
    }
}

extern "C" void kernel_launch(void* const* d_in, const int* in_sizes, int n_in,
                              void* d_out, int out_size, void* d_ws, size_t ws_size,
                              hipStream_t stream) {
    const float* X    = (const float*)d_in[0];
    const float* mask = (const float*)d_in[1];
    const float* Wq   = (const float*)d_in[2];
    const float* bq   = (const float*)d_in[3];
    const float* Wk   = (const float*)d_in[4];
    const float* bk   = (const float*)d_in[5];
    const float* Wv   = (const float*)d_in[6];
    const float* bv   = (const float*)d_in[7];
    const float* Ek   = (const float*)d_in[8];
    const float* Ev   = (const float*)d_in[9];
    float* out        = (float*)d_out;

    char* ws = (char*)d_ws;
    const size_t SZ_QKV = (size_t)BSZ * NH * SEQ * HD * 2;   // 6,291,456 B each
    const size_t SZ_W   = (size_t)HDIM * HDIM * 2;           // 1,179,648 B each
    _Float16* Qh  = (_Float16*)(ws);
    _Float16* Kh  = (_Float16*)(ws + SZ_QKV);
    short*    Vb  = (short*)   (ws + 2 * SZ_QKV);
    _Float16* Xh  = (_Float16*)(ws + 3 * SZ_QKV);
    _Float16* Wtq = (_Float16*)(ws + 4 * SZ_QKV);
    _Float16* Wtk = (_Float16*)(ws + 4 * SZ_QKV + SZ_W);
    _Float16* Wtv = (_Float16*)(ws + 4 * SZ_QKV + 2 * SZ_W);
    _Float16* Ekh = (_Float16*)(ws + 4 * SZ_QKV + 3 * SZ_W);
    short*    Evt = (short*)   (ws + 4 * SZ_QKV + 3 * SZ_W + 20480);

    convert_f16_kernel<<<(NXCHUNK + NECHUNK + NEVCHUNK + 255) / 256, 256, 0, stream>>>(
        X, Ek, Ev, Xh, Ekh, Evt);
    transpose_w_kernel<<<dim3(12, 12, 3), 256, 0, stream>>>(Wq, Wk, Wv, Wtq, Wtk, Wtv);
    qkv_mfma_kernel<<<576, 256, 0, stream>>>(Xh, Wtq, Wtk, Wtv, bq, bk, bv, Qh, Kh, Vb);
    attn_mfma_kernel<<<dim3(SEQ / 64, NH, BSZ), 256, 0, stream>>>(Qh, Kh, Vb, mask, Ekh, Evt, out);
}